// Round 19
// baseline (274.373 us; speedup 1.0000x reference)
//
#include <hip/hip_runtime.h>
#include <hip/hip_bf16.h>

#define MASK_ID 3
#define MAX_SEN 128
#define NB 8
#define SEQ 8192
#define EMB 1024
#define DIM 128

typedef __attribute__((ext_vector_type(8))) short short8v;   // 8 bf16
typedef __attribute__((ext_vector_type(4))) float f32x4;     // MFMA accumulator

#define MFMA(a, b, c) __builtin_amdgcn_mfma_f32_16x16x32_bf16(a, b, c, 0, 0, 0)

// fp32 -> bf16 RNE
__device__ __forceinline__ short f2b(float x) {
    union { float f; unsigned u; } v; v.f = x;
    unsigned r = (v.u + 0x7FFFu + ((v.u >> 16) & 1u)) >> 16;
    return (short)r;
}

// bf16 (raw short) -> fp32
__device__ __forceinline__ float b2f(short s) {
    return __uint_as_float(((unsigned)(unsigned short)s) << 16);
}

// hardware packed cvt: [bf16(b)|bf16(a)]
__device__ __forceinline__ unsigned cvtpk(float a, float b) {
    unsigned r;
    asm("v_cvt_pk_bf16_f32 %0, %1, %2" : "=v"(r) : "v"(a), "v"(b));
    return r;
}

// ---------------- Kernel 1: per-row scan -> mask positions + nvis ----------------
__global__ __launch_bounds__(1024) void seg_kernel(const int* __restrict__ ids,
                                                   int* __restrict__ pos,
                                                   int* __restrict__ nvis) {
    int b = blockIdx.x;
    int tid = threadIdx.x;
    __shared__ int sc[1024];
    __shared__ int sc2[1024];
    const int PER = SEQ / 1024;  // 8
    int base = b * SEQ + tid * PER;

    int ids_l[PER];
    int cnt = 0;
    #pragma unroll
    for (int j = 0; j < PER; j++) {
        ids_l[j] = ids[base + j];
        cnt += (ids_l[j] == MASK_ID) ? 1 : 0;
    }
    if (tid < MAX_SEN) pos[b * MAX_SEN + tid] = -1;
    sc[tid] = cnt;
    __syncthreads();

    int* src = sc;
    int* dst = sc2;
    for (int off = 1; off < 1024; off <<= 1) {
        int v = src[tid];
        if (tid >= off) v += src[tid - off];
        dst[tid] = v;
        __syncthreads();
        int* t = src; src = dst; dst = t;
    }
    int incl = src[tid];
    int run = incl - cnt;  // exclusive prefix

    #pragma unroll
    for (int j = 0; j < PER; j++) {
        if (ids_l[j] == MASK_ID) {
            run++;
            if (run <= MAX_SEN) pos[b * MAX_SEN + run - 1] = tid * PER + j;
        }
        int nv = run; if (nv > MAX_SEN) nv = MAX_SEN;
        nvis[base + j] = nv;
    }
}

// ---------------- Kernel 2: weights -> bf16 FRAGMENT-TILED layouts (gather-style) ----------------
__global__ __launch_bounds__(256) void prep_w(const float* __restrict__ Wq,
                                              const float* __restrict__ Wo,
                                              short* __restrict__ WqTt,
                                              short* __restrict__ WoTt) {
    int t = blockIdx.x * 256 + threadIdx.x;        // 0 .. 16383
    {   // WqTt: frag fid = (c*2+ks)*8+cf; e = c*64+ks*32+(lp>>4)*8+j; d = cf*16+(lp&15)
        int fid = t >> 6, lp = t & 63;
        int c = fid >> 4, ks = (fid >> 3) & 1, cf = fid & 7;
        int e0 = c * 64 + ks * 32 + (lp >> 4) * 8;
        int d = cf * 16 + (lp & 15);
        short8v v;
        #pragma unroll
        for (int j = 0; j < 8; j++) v[j] = f2b(Wq[(size_t)(e0 + j) * 128 + d]);
        *(short8v*)(WqTt + fid * 512 + lp * 8) = v;
    }
    {   // WoTt: frag fid = ef*4+kk; e = ef*16+(lp&15); dd = kk*32+(lp>>4)*8+j
        int fid = t >> 6, lp = t & 63;
        int ef = fid >> 2, kk = fid & 3;
        int e = ef * 16 + (lp & 15);
        int dd0 = kk * 32 + (lp >> 4) * 8;
        short8v v;
        #pragma unroll
        for (int j = 0; j < 8; j++) v[j] = f2b(Wo[(size_t)(dd0 + j) * 1024 + e]);
        *(short8v*)(WoTt + fid * 512 + lp * 8) = v;
    }
}

// ---------------- Kernel 3: static+kv, 4 m-rows/block, 256 threads (e-split) ----------------
__global__ __launch_bounds__(256) void statkv_kernel(const float* __restrict__ hidden,
                                                     const float* __restrict__ Wv, const float* __restrict__ bv,
                                                     const float* __restrict__ Wk, const float* __restrict__ bk,
                                                     const float* __restrict__ Wvt, const float* __restrict__ bvt,
                                                     const int* __restrict__ pos,
                                                     short* __restrict__ k_t, short* __restrict__ vT_t) {
    int mg = blockIdx.x;           // 0..31  (m = mg*4 + j)
    int b  = blockIdx.y;
    int tid = threadIdx.x;
    int d  = tid & 127;
    int half = tid >> 7;           // 0..1
    __shared__ float h[4][1024];   // 16 KB (reused as reduce scratch later)
    __shared__ float part[2][4][128]; // 4 KB
    __shared__ float st[4][128];   // 2 KB
    int m0 = mg * 4;

    #pragma unroll
    for (int j = 0; j < 4; j++) {
        int p = pos[b * MAX_SEN + m0 + j];       // uniform per j
        const float* hp = hidden + ((size_t)b * SEQ + (p < 0 ? 0 : p)) * EMB;
        float4 v = {0.f, 0.f, 0.f, 0.f};
        if (p >= 0) v = *(const float4*)(hp + tid * 4);
        *(float4*)&h[j][tid * 4] = v;
    }
    __syncthreads();

    float a0 = 0.f, a1 = 0.f, a2 = 0.f, a3 = 0.f;
    int ebase = half * 512;
    for (int e = ebase; e < ebase + 512; e += 4) {
        float w0 = Wv[(size_t)e * 128 + d];
        float w1 = Wv[(size_t)(e + 1) * 128 + d];
        float w2 = Wv[(size_t)(e + 2) * 128 + d];
        float w3 = Wv[(size_t)(e + 3) * 128 + d];
        float4 h0 = *(const float4*)&h[0][e];
        float4 h1 = *(const float4*)&h[1][e];
        float4 h2 = *(const float4*)&h[2][e];
        float4 h3 = *(const float4*)&h[3][e];
        a0 += h0.x * w0 + h0.y * w1 + h0.z * w2 + h0.w * w3;
        a1 += h1.x * w0 + h1.y * w1 + h1.z * w2 + h1.w * w3;
        a2 += h2.x * w0 + h2.y * w1 + h2.z * w2 + h2.w * w3;
        a3 += h3.x * w0 + h3.y * w1 + h3.z * w2 + h3.w * w3;
    }
    part[half][0][d] = a0;
    part[half][1][d] = a1;
    part[half][2][d] = a2;
    part[half][3][d] = a3;
    __syncthreads();
    if (half == 0) {
        float bvd = bv[d];
        #pragma unroll
        for (int j = 0; j < 4; j++)
            st[j][d] = bvd + part[0][j][d] + part[1][j][d];
    }
    __syncthreads();

    // K/V GEMM: half h covers e in [h*64, h*64+64)
    float k0 = 0.f, k1 = 0.f, k2 = 0.f, k3 = 0.f;
    float v0 = 0.f, v1 = 0.f, v2 = 0.f, v3 = 0.f;
    for (int e = half * 64; e < half * 64 + 64; e += 2) {
        float wk0 = Wk[(e) * 128 + d],  wk1 = Wk[(e + 1) * 128 + d];
        float wv0 = Wvt[(e) * 128 + d], wv1 = Wvt[(e + 1) * 128 + d];
        float s00 = st[0][e], s01 = st[0][e + 1];
        float s10 = st[1][e], s11 = st[1][e + 1];
        float s20 = st[2][e], s21 = st[2][e + 1];
        float s30 = st[3][e], s31 = st[3][e + 1];
        k0 += s00 * wk0 + s01 * wk1;  v0 += s00 * wv0 + s01 * wv1;
        k1 += s10 * wk0 + s11 * wk1;  v1 += s10 * wv0 + s11 * wv1;
        k2 += s20 * wk0 + s21 * wk1;  v2 += s20 * wv0 + s21 * wv1;
        k3 += s30 * wk0 + s31 * wk1;  v3 += s30 * wv0 + s31 * wv1;
    }
    // reduce via scratch in h (dead): slot = half*2 + which (0=K,1=V)
    float* scr = (float*)h;   // [4 slots][4 rows][128]
    scr[((half * 2 + 0) * 4 + 0) * 128 + d] = k0;
    scr[((half * 2 + 0) * 4 + 1) * 128 + d] = k1;
    scr[((half * 2 + 0) * 4 + 2) * 128 + d] = k2;
    scr[((half * 2 + 0) * 4 + 3) * 128 + d] = k3;
    scr[((half * 2 + 1) * 4 + 0) * 128 + d] = v0;
    scr[((half * 2 + 1) * 4 + 1) * 128 + d] = v1;
    scr[((half * 2 + 1) * 4 + 2) * 128 + d] = v2;
    scr[((half * 2 + 1) * 4 + 3) * 128 + d] = v3;
    __syncthreads();
    if (half == 0) {
        float bkd = bk[d];
        #pragma unroll
        for (int j = 0; j < 4; j++) {
            int m = m0 + j;
            float kvj = bkd + scr[(0 * 4 + j) * 128 + d] + scr[(2 * 4 + j) * 128 + d];
            int kk = d >> 5, lq = (d >> 3) & 3, jj = d & 7;
            int fid = (m >> 4) * 4 + kk;
            k_t[(b << 14) + fid * 512 + (lq * 16 + (m & 15)) * 8 + jj] = f2b(kvj);
        }
    } else {
        float bvtd = bvt[d];
        #pragma unroll
        for (int j = 0; j < 4; j++) {
            int m = m0 + j;
            float vvj = bvtd + scr[(1 * 4 + j) * 128 + d] + scr[(3 * 4 + j) * 128 + d];
            int df = d >> 4, kk2 = m >> 5, lq2 = (m >> 3) & 3, j2 = m & 7;
            int fid2 = df * 4 + kk2;
            vT_t[(b << 14) + fid2 * 512 + (lq2 * 16 + (d & 15)) * 8 + j2] = f2b(vvj);
        }
    }
}

// ---------------- Kernel 4: fused MFMA attention, 64 tokens/block, 32KB LDS ----------------
// R18 structure with lg stored as bf16 (16KB) -> LDS 48->32KB -> 4 blocks/CU.
// Layout: ph1: qP [0,16K), Ab [16K,24K). ph2: lg bf16 [16K,32K). ph3: pP [0,16K).
// ph4: od [16K,32K). ph5: C-stage [0,16.6K).
__global__ __launch_bounds__(256, 4) void attn_kernel(
    const float* __restrict__ hidden,
    const short* __restrict__ WqTt, const float* __restrict__ bq,
    const short* __restrict__ k_t, const short* __restrict__ vT_t,
    const short* __restrict__ WoTt, const float* __restrict__ bo,
    const int* __restrict__ nvis,
    float* __restrict__ out) {
    // XCD swizzle: XCD x owns batch x (K/V L2-resident)
    int wg = (blockIdx.x & 7) * 128 + (blockIdx.x >> 3);
    int b  = wg >> 7;
    int s0 = (wg & 127) * 64;
    int tid = threadIdx.x;
    int lane = tid & 63;
    int w  = tid >> 6;             // wave 0..3
    int lr = lane & 15;
    int lq = lane >> 4;            // quarter 0..3

    __shared__ __align__(16) char SH[32768];
    char* qPc = SH;                // [0,16K)
    char* Ab  = SH + 16384;        // [16K,24K) phase 1
    char* lgc = SH + 16384;        // [16K,32K) phase 2-3 (bf16 logits)
    char* pPc = SH;                // [0,16K)  phase 3-4
    char* odc = SH + 16384;        // [16K,32K) phase 4-5

    const size_t hrow = (size_t)b * SEQ + s0;
    f32x4 zero = {0.f, 0.f, 0.f, 0.f};

    // ================= phase 1: q = (H @ Wq + bq) * scale =================
    f32x4 acc[4][2];
    #pragma unroll
    for (int rf = 0; rf < 4; rf++) { acc[rf][0] = zero; acc[rf][1] = zero; }

    // Coalesced staging map: instr g (0..3), thread t: row = g*16 + (t>>4),
    // 4 fp32 at float-index (t&15)*4. Per wave-instruction: 4 rows x 256B.
    int rsub = tid >> 4;           // 0..15
    int cfl  = (tid & 15) * 4;
    const float* hA0 = hidden + (hrow + 0 * 16 + rsub) * EMB + cfl;
    const float* hA1 = hidden + (hrow + 1 * 16 + rsub) * EMB + cfl;
    const float* hA2 = hidden + (hrow + 2 * 16 + rsub) * EMB + cfl;
    const float* hA3 = hidden + (hrow + 3 * 16 + rsub) * EMB + cfl;
    int swzA = (rsub & 7) << 4;
    int dA0 = (0 * 16 + rsub) * 128 + (((tid & 15) * 8) ^ swzA);
    int dA1 = (1 * 16 + rsub) * 128 + (((tid & 15) * 8) ^ swzA);
    int dA2 = (2 * 16 + rsub) * 128 + (((tid & 15) * 8) ^ swzA);
    int dA3 = (3 * 16 + rsub) * 128 + (((tid & 15) * 8) ^ swzA);

    float4 pa0[4], pa1[4], pa2[4];
    short8v Wa[4], Wb[4];

#define LOADA(C, PA) do { \
    PA[0] = *(const float4*)(hA0 + (C) * 64); \
    PA[1] = *(const float4*)(hA1 + (C) * 64); \
    PA[2] = *(const float4*)(hA2 + (C) * 64); \
    PA[3] = *(const float4*)(hA3 + (C) * 64); } while (0)

#define LOADW(C, W) do { \
    const short* wp = WqTt + ((C) * 16 + 2 * w) * 512 + lane * 8; \
    W[0] = *(const short8v*)(wp); \
    W[1] = *(const short8v*)(wp + 512); \
    W[2] = *(const short8v*)(wp + 8 * 512); \
    W[3] = *(const short8v*)(wp + 9 * 512); } while (0)

#define STORE_A(PA) do { \
    unsigned long long v0_ = (unsigned long long)cvtpk(PA[0].z, PA[0].w) << 32 | cvtpk(PA[0].x, PA[0].y); \
    unsigned long long v1_ = (unsigned long long)cvtpk(PA[1].z, PA[1].w) << 32 | cvtpk(PA[1].x, PA[1].y); \
    unsigned long long v2_ = (unsigned long long)cvtpk(PA[2].z, PA[2].w) << 32 | cvtpk(PA[2].x, PA[2].y); \
    unsigned long long v3_ = (unsigned long long)cvtpk(PA[3].z, PA[3].w) << 32 | cvtpk(PA[3].x, PA[3].y); \
    *(unsigned long long*)(Ab + dA0) = v0_; \
    *(unsigned long long*)(Ab + dA1) = v1_; \
    *(unsigned long long*)(Ab + dA2) = v2_; \
    *(unsigned long long*)(Ab + dA3) = v3_; } while (0)

#define COMPUTE(W) do { \
    _Pragma("unroll") \
    for (int ks = 0; ks < 2; ks++) { \
        _Pragma("unroll") \
        for (int rf = 0; rf < 4; rf++) { \
            int row = rf * 16 + lr; \
            short8v fa = *(short8v*)(Ab + ((row * 128 + ks * 64 + lq * 16) ^ ((row & 7) << 4))); \
            acc[rf][0] = MFMA(fa, W[ks * 2 + 0], acc[rf][0]); \
            acc[rf][1] = MFMA(fa, W[ks * 2 + 1], acc[rf][1]); \
        } } } while (0)

// R12/R16 schedule: vmcnt never force-drains; LOADW(c+2) after COMPUTE.
#define ITER(c, PA, WW, DO_A, DO_W) do { \
    __builtin_amdgcn_s_barrier();                 /* readers of chunk c-1 done */ \
    STORE_A(PA);                                  /* counted wait: A(c)       */ \
    if (DO_A) LOADA((c) + 3, PA); \
    asm volatile("s_waitcnt lgkmcnt(0)" ::: "memory"); \
    __builtin_amdgcn_sched_barrier(0); \
    __builtin_amdgcn_s_barrier();                 /* chunk c visible          */ \
    COMPUTE(WW);                                  /* counted wait: W(c)       */ \
    if (DO_W) LOADW((c) + 2, WW);                 /* refill consumed slot     */ \
    } while (0)

    // prologue — queue: W0, W1, A0, A1, A2
    LOADW(0, Wa);
    LOADW(1, Wb);
    LOADA(0, pa0);
    LOADA(1, pa1);
    LOADA(2, pa2);

    ITER(0,  pa0, Wa, 1, 1);
    ITER(1,  pa1, Wb, 1, 1);
    ITER(2,  pa2, Wa, 1, 1);
    ITER(3,  pa0, Wb, 1, 1);
    ITER(4,  pa1, Wa, 1, 1);
    ITER(5,  pa2, Wb, 1, 1);
    ITER(6,  pa0, Wa, 1, 1);
    ITER(7,  pa1, Wb, 1, 1);
    ITER(8,  pa2, Wa, 1, 1);
    ITER(9,  pa0, Wb, 1, 1);
    ITER(10, pa1, Wa, 1, 1);
    ITER(11, pa2, Wb, 1, 1);
    ITER(12, pa0, Wa, 1, 1);
    ITER(13, pa1, Wb, 0, 1);
    ITER(14, pa2, Wa, 0, 0);
    ITER(15, pa0, Wb, 0, 0);

    {
        const float scale = 0.08838834764831845f;  // 128^-0.5
        int d0 = w * 32 + lr;
        float bq0 = bq[d0], bq1 = bq[d0 + 16];
        #pragma unroll
        for (int rf = 0; rf < 4; rf++)
            #pragma unroll
            for (int r = 0; r < 4; r++) {
                int row = rf * 16 + lq * 4 + r;
                int x = (row & 7) << 4;
                *(short*)(qPc + row * 256 + ((d0 * 2) ^ x))        = f2b((acc[rf][0][r] + bq0) * scale);
                *(short*)(qPc + row * 256 + (((d0 + 16) * 2) ^ x)) = f2b((acc[rf][1][r] + bq1) * scale);
            }
    }
    __syncthreads();   // B1: q visible; Ab dead -> lg region live

    // ================= phase 2: logits = q @ K^T (bf16 store) =================
    {
        f32x4 l[4][2];
        #pragma unroll
        for (int rf = 0; rf < 4; rf++) { l[rf][0] = zero; l[rf][1] = zero; }
        const short* kbase = k_t + (b << 14) + (2 * w) * 4 * 512 + lane * 8;
        #pragma unroll
        for (int kk = 0; kk < 4; kk++) {
            const short8v fb0 = *(const short8v*)(kbase + kk * 512);
            const short8v fb1 = *(const short8v*)(kbase + (4 + kk) * 512);
            #pragma unroll
            for (int rf = 0; rf < 4; rf++) {
                int row = rf * 16 + lr;
                int x = (row & 7) << 4;
                short8v fa = *(short8v*)(qPc + row * 256 + ((kk * 64 + lq * 16) ^ x));
                l[rf][0] = MFMA(fa, fb0, l[rf][0]);
                l[rf][1] = MFMA(fa, fb1, l[rf][1]);
            }
        }
        #pragma unroll
        for (int rf = 0; rf < 4; rf++)
            #pragma unroll
            for (int r = 0; r < 4; r++) {
                int row = rf * 16 + lq * 4 + r;
                int x = (row & 7) << 4;
                *(short*)(lgc + row * 256 + (((w * 32 + lr) * 2) ^ x))        = f2b(l[rf][0][r]);
                *(short*)(lgc + row * 256 + (((w * 32 + 16 + lr) * 2) ^ x))   = f2b(l[rf][1][r]);
            }
    }
    __syncthreads();   // B2: logits visible; qP dead -> pP region live

    // ============ phase 3: masked softmax (4 threads/token, 32 m each) ============
    {
        int t = tid >> 2, sub = tid & 3;
        int nv = nvis[b * SEQ + s0 + t];
        int x = (t & 7) << 4;
        float pv[32];
        #pragma unroll
        for (int u = 0; u < 4; u++) {
            short8v v = *(const short8v*)(lgc + t * 256 + ((sub * 64 + u * 16) ^ x));
            #pragma unroll
            for (int i = 0; i < 8; i++) pv[u * 8 + i] = b2f(v[i]);
        }
        int base_m = sub * 32;
        float mx = -3.0e38f;
        #pragma unroll
        for (int i = 0; i < 32; i++)
            mx = (base_m + i < nv) ? fmaxf(mx, pv[i]) : mx;
        mx = fmaxf(mx, __shfl_xor(mx, 1));
        mx = fmaxf(mx, __shfl_xor(mx, 2));
        float sum = 0.f;
        #pragma unroll
        for (int i = 0; i < 32; i++) {
            float e = (base_m + i < nv) ? __expf(pv[i] - mx) : 0.f;
            pv[i] = e;
            sum += e;
        }
        sum += __shfl_xor(sum, 1);
        sum += __shfl_xor(sum, 2);
        float inv = (nv > 0) ? 1.0f / sum : 0.f;

        // pP region ([0,16K)) = old qP, dead since B2; lg reads target [16K,32K).
        #pragma unroll
        for (int u = 0; u < 4; u++) {
            union { short8v s; unsigned uu[4]; } p;
            #pragma unroll
            for (int i = 0; i < 4; i++)
                p.uu[i] = cvtpk(pv[u * 8 + 2 * i] * inv, pv[u * 8 + 2 * i + 1] * inv);
            *(short8v*)(pPc + t * 256 + ((sub * 64 + u * 16) ^ x)) = p.s;
        }
    }
    __syncthreads();   // B4: P visible; lg dead -> od region live

    // ================= phase 4: od = P @ V =================
    {
        f32x4 o[4][2];
        #pragma unroll
        for (int rf = 0; rf < 4; rf++) { o[rf][0] = zero; o[rf][1] = zero; }
        const short* vbase = vT_t + (b << 14) + (2 * w) * 4 * 512 + lane * 8;
        #pragma unroll
        for (int kk = 0; kk < 4; kk++) {
            const short8v fb0 = *(const short8v*)(vbase + kk * 512);
            const short8v fb1 = *(const short8v*)(vbase + (4 + kk) * 512);
            #pragma unroll
            for (int rf = 0; rf < 4; rf++) {
                int row = rf * 16 + lr;
                int x = (row & 7) << 4;
                short8v fa = *(short8v*)(pPc + row * 256 + ((kk * 64 + lq * 16) ^ x));
                o[rf][0] = MFMA(fa, fb0, o[rf][0]);
                o[rf][1] = MFMA(fa, fb1, o[rf][1]);
            }
        }
        int d0 = w * 32 + lr;
        #pragma unroll
        for (int rf = 0; rf < 4; rf++)
            #pragma unroll
            for (int r = 0; r < 4; r++) {
                int row = rf * 16 + lq * 4 + r;
                int x = (row & 7) << 4;
                *(short*)(odc + row * 256 + ((d0 * 2) ^ x))        = f2b(o[rf][0][r]);
                *(short*)(odc + row * 256 + (((d0 + 16) * 2) ^ x)) = f2b(o[rf][1][r]);
            }
    }
    __syncthreads();   // B5: od visible

    // ===== phase 5: out = od @ Wo + bo — full-line writes via LDS C-stage =====
    {
        short8v af[4][4];
        #pragma unroll
        for (int rf = 0; rf < 4; rf++)
            #pragma unroll
            for (int kk = 0; kk < 4; kk++) {
                int row = rf * 16 + lr;
                int x = (row & 7) << 4;
                af[rf][kk] = *(short8v*)(odc + row * 256 + ((kk * 64 + lq * 16) ^ x));
            }
        __syncthreads();   // B6: od fully consumed -> SH free for C-stage

        float* cst = (float*)SH;        // 16 rows x 260 dwords (1040B stride)
        int srow2 = tid >> 4;           // coop-store row 0..15
        int scidx = (tid & 15) * 4;     // coop-store col base (floats)

        #pragma unroll
        for (int grp = 0; grp < 4; grp++) {
            f32x4 ac[4][4];
            #pragma unroll
            for (int rf = 0; rf < 4; rf++)
                #pragma unroll
                for (int cf = 0; cf < 4; cf++) ac[rf][cf] = zero;
            #pragma unroll
            for (int kk = 0; kk < 4; kk++) {
                #pragma unroll
                for (int cf = 0; cf < 4; cf++) {
                    const short8v bb = *(const short8v*)(WoTt
                        + ((grp * 16 + w * 4 + cf) * 4 + kk) * 512 + lane * 8);
                    #pragma unroll
                    for (int rf = 0; rf < 4; rf++)
                        ac[rf][cf] = MFMA(af[rf][kk], bb, ac[rf][cf]);
                }
            }
            #pragma unroll
            for (int rf = 0; rf < 4; rf++) {
                #pragma unroll
                for (int cf = 0; cf < 4; cf++)
                    #pragma unroll
                    for (int r = 0; r < 4; r++)
                        cst[(lq * 4 + r) * 260 + w * 64 + cf * 16 + lr] = ac[rf][cf][r];
                __syncthreads();
                #pragma unroll
                for (int i = 0; i < 4; i++) {
                    int cidx = scidx + i * 64;
                    float4 v = *(const float4*)(cst + srow2 * 260 + cidx);
                    float4 b4 = *(const float4*)(bo + grp * 256 + cidx);
                    v.x += b4.x; v.y += b4.y; v.z += b4.z; v.w += b4.w;
                    *(float4*)(&out[(hrow + rf * 16 + srow2) * EMB + grp * 256 + cidx]) = v;
                }
                __syncthreads();
            }
        }
    }
}

extern "C" void kernel_launch(void* const* d_in, const int* in_sizes, int n_in,
                              void* d_out, int out_size, void* d_ws, size_t ws_size,
                              hipStream_t stream) {
    const int*   ids    = (const int*)d_in[0];
    const float* hidden = (const float*)d_in[1];
    const float* Wv     = (const float*)d_in[2];
    const float* bv     = (const float*)d_in[3];
    const float* Wq     = (const float*)d_in[4];
    const float* bq     = (const float*)d_in[5];
    const float* Wk     = (const float*)d_in[6];
    const float* bk     = (const float*)d_in[7];
    const float* Wvt    = (const float*)d_in[8];
    const float* bvt    = (const float*)d_in[9];
    const float* Wo     = (const float*)d_in[10];
    const float* bo     = (const float*)d_in[11];

    char* ws = (char*)d_ws;
    int*   pos   = (int*)ws;                                   // 4 KB
    int*   nvis  = (int*)(ws + (4 << 10));                     // 256 KB
    short* k_t   = (short*)(ws + (260 << 10));                 // 256 KB tiled
    short* vT_t  = (short*)(ws + (516 << 10));                 // 256 KB tiled
    short* WqTt  = (short*)(ws + (772 << 10));                 // 256 KB tiled
    short* WoTt  = (short*)(ws + (1028 << 10));                // 256 KB tiled

    seg_kernel<<<NB, 1024, 0, stream>>>(ids, pos, nvis);
    prep_w<<<64, 256, 0, stream>>>(Wq, Wo, WqTt, WoTt);
    dim3 g2(32, NB);
    statkv_kernel<<<g2, 256, 0, stream>>>(hidden, Wv, bv, Wk, bk, Wvt, bvt, pos, k_t, vT_t);
    attn_kernel<<<NB * (SEQ / 64), 256, 0, stream>>>(hidden, WqTt, bq, k_t, vT_t, WoTt, bo,
                                                     nvis, (float*)d_out);
}

// Round 20
// 204.902 us; speedup vs baseline: 1.3390x; 1.3390x over previous
//
#include <hip/hip_runtime.h>
#include <hip/hip_bf16.h>

#define MASK_ID 3
#define MAX_SEN 128
#define NB 8
#define SEQ 8192
#define EMB 1024
#define DIM 128

typedef __attribute__((ext_vector_type(8))) short short8v;   // 8 bf16
typedef __attribute__((ext_vector_type(4))) float f32x4;     // MFMA accumulator

#define MFMA(a, b, c) __builtin_amdgcn_mfma_f32_16x16x32_bf16(a, b, c, 0, 0, 0)

// fp32 -> bf16 RNE
__device__ __forceinline__ short f2b(float x) {
    union { float f; unsigned u; } v; v.f = x;
    unsigned r = (v.u + 0x7FFFu + ((v.u >> 16) & 1u)) >> 16;
    return (short)r;
}

// hardware packed cvt: [bf16(b)|bf16(a)]
__device__ __forceinline__ unsigned cvtpk(float a, float b) {
    unsigned r;
    asm("v_cvt_pk_bf16_f32 %0, %1, %2" : "=v"(r) : "v"(a), "v"(b));
    return r;
}

// ---------------- Kernel 1: per-row scan -> mask positions + nvis ----------------
__global__ __launch_bounds__(1024) void seg_kernel(const int* __restrict__ ids,
                                                   int* __restrict__ pos,
                                                   int* __restrict__ nvis) {
    int b = blockIdx.x;
    int tid = threadIdx.x;
    __shared__ int sc[1024];
    __shared__ int sc2[1024];
    const int PER = SEQ / 1024;  // 8
    int base = b * SEQ + tid * PER;

    int ids_l[PER];
    int cnt = 0;
    #pragma unroll
    for (int j = 0; j < PER; j++) {
        ids_l[j] = ids[base + j];
        cnt += (ids_l[j] == MASK_ID) ? 1 : 0;
    }
    if (tid < MAX_SEN) pos[b * MAX_SEN + tid] = -1;
    sc[tid] = cnt;
    __syncthreads();

    int* src = sc;
    int* dst = sc2;
    for (int off = 1; off < 1024; off <<= 1) {
        int v = src[tid];
        if (tid >= off) v += src[tid - off];
        dst[tid] = v;
        __syncthreads();
        int* t = src; src = dst; dst = t;
    }
    int incl = src[tid];
    int run = incl - cnt;  // exclusive prefix

    #pragma unroll
    for (int j = 0; j < PER; j++) {
        if (ids_l[j] == MASK_ID) {
            run++;
            if (run <= MAX_SEN) pos[b * MAX_SEN + run - 1] = tid * PER + j;
        }
        int nv = run; if (nv > MAX_SEN) nv = MAX_SEN;
        nvis[base + j] = nv;
    }
}

// ---------------- Kernel 2: weights -> bf16 FRAGMENT-TILED layouts (gather-style) ----------------
__global__ __launch_bounds__(256) void prep_w(const float* __restrict__ Wq,
                                              const float* __restrict__ Wo,
                                              short* __restrict__ WqTt,
                                              short* __restrict__ WoTt) {
    int t = blockIdx.x * 256 + threadIdx.x;        // 0 .. 16383
    {   // WqTt: frag fid = (c*2+ks)*8+cf; e = c*64+ks*32+(lp>>4)*8+j; d = cf*16+(lp&15)
        int fid = t >> 6, lp = t & 63;
        int c = fid >> 4, ks = (fid >> 3) & 1, cf = fid & 7;
        int e0 = c * 64 + ks * 32 + (lp >> 4) * 8;
        int d = cf * 16 + (lp & 15);
        short8v v;
        #pragma unroll
        for (int j = 0; j < 8; j++) v[j] = f2b(Wq[(size_t)(e0 + j) * 128 + d]);
        *(short8v*)(WqTt + fid * 512 + lp * 8) = v;
    }
    {   // WoTt: frag fid = ef*4+kk; e = ef*16+(lp&15); dd = kk*32+(lp>>4)*8+j
        int fid = t >> 6, lp = t & 63;
        int ef = fid >> 2, kk = fid & 3;
        int e = ef * 16 + (lp & 15);
        int dd0 = kk * 32 + (lp >> 4) * 8;
        short8v v;
        #pragma unroll
        for (int j = 0; j < 8; j++) v[j] = f2b(Wo[(size_t)(dd0 + j) * 1024 + e]);
        *(short8v*)(WoTt + fid * 512 + lp * 8) = v;
    }
}

// ---------------- Kernel 3: static+kv, 4 m-rows/block, 256 threads (e-split) ----------------
// thread (d = tid&127, half = tid>>7): big GEMM over 512 e's, K/V GEMM over 64
// e's; partials reduced via LDS. Same 256-block grid as R16, half the serial path.
__global__ __launch_bounds__(256) void statkv_kernel(const float* __restrict__ hidden,
                                                     const float* __restrict__ Wv, const float* __restrict__ bv,
                                                     const float* __restrict__ Wk, const float* __restrict__ bk,
                                                     const float* __restrict__ Wvt, const float* __restrict__ bvt,
                                                     const int* __restrict__ pos,
                                                     short* __restrict__ k_t, short* __restrict__ vT_t) {
    int mg = blockIdx.x;           // 0..31  (m = mg*4 + j)
    int b  = blockIdx.y;
    int tid = threadIdx.x;
    int d  = tid & 127;
    int half = tid >> 7;           // 0..1
    __shared__ float h[4][1024];   // 16 KB (reused as reduce scratch later)
    __shared__ float part[2][4][128]; // 4 KB
    __shared__ float st[4][128];   // 2 KB
    int m0 = mg * 4;

    #pragma unroll
    for (int j = 0; j < 4; j++) {
        int p = pos[b * MAX_SEN + m0 + j];       // uniform per j
        const float* hp = hidden + ((size_t)b * SEQ + (p < 0 ? 0 : p)) * EMB;
        float4 v = {0.f, 0.f, 0.f, 0.f};
        if (p >= 0) v = *(const float4*)(hp + tid * 4);
        *(float4*)&h[j][tid * 4] = v;
    }
    __syncthreads();

    float a0 = 0.f, a1 = 0.f, a2 = 0.f, a3 = 0.f;
    int ebase = half * 512;
    for (int e = ebase; e < ebase + 512; e += 4) {
        float w0 = Wv[(size_t)e * 128 + d];
        float w1 = Wv[(size_t)(e + 1) * 128 + d];
        float w2 = Wv[(size_t)(e + 2) * 128 + d];
        float w3 = Wv[(size_t)(e + 3) * 128 + d];
        float4 h0 = *(const float4*)&h[0][e];
        float4 h1 = *(const float4*)&h[1][e];
        float4 h2 = *(const float4*)&h[2][e];
        float4 h3 = *(const float4*)&h[3][e];
        a0 += h0.x * w0 + h0.y * w1 + h0.z * w2 + h0.w * w3;
        a1 += h1.x * w0 + h1.y * w1 + h1.z * w2 + h1.w * w3;
        a2 += h2.x * w0 + h2.y * w1 + h2.z * w2 + h2.w * w3;
        a3 += h3.x * w0 + h3.y * w1 + h3.z * w2 + h3.w * w3;
    }
    part[half][0][d] = a0;
    part[half][1][d] = a1;
    part[half][2][d] = a2;
    part[half][3][d] = a3;
    __syncthreads();
    if (half == 0) {
        float bvd = bv[d];
        #pragma unroll
        for (int j = 0; j < 4; j++)
            st[j][d] = bvd + part[0][j][d] + part[1][j][d];
    }
    __syncthreads();

    // K/V GEMM: half h covers e in [h*64, h*64+64)
    float k0 = 0.f, k1 = 0.f, k2 = 0.f, k3 = 0.f;
    float v0 = 0.f, v1 = 0.f, v2 = 0.f, v3 = 0.f;
    for (int e = half * 64; e < half * 64 + 64; e += 2) {
        float wk0 = Wk[(e) * 128 + d],  wk1 = Wk[(e + 1) * 128 + d];
        float wv0 = Wvt[(e) * 128 + d], wv1 = Wvt[(e + 1) * 128 + d];
        float s00 = st[0][e], s01 = st[0][e + 1];
        float s10 = st[1][e], s11 = st[1][e + 1];
        float s20 = st[2][e], s21 = st[2][e + 1];
        float s30 = st[3][e], s31 = st[3][e + 1];
        k0 += s00 * wk0 + s01 * wk1;  v0 += s00 * wv0 + s01 * wv1;
        k1 += s10 * wk0 + s11 * wk1;  v1 += s10 * wv0 + s11 * wv1;
        k2 += s20 * wk0 + s21 * wk1;  v2 += s20 * wv0 + s21 * wv1;
        k3 += s30 * wk0 + s31 * wk1;  v3 += s30 * wv0 + s31 * wv1;
    }
    // reduce via scratch in h (dead): slot = half*2 + which (0=K,1=V)
    float* scr = (float*)h;   // [4 slots][4 rows][128]
    scr[((half * 2 + 0) * 4 + 0) * 128 + d] = k0;
    scr[((half * 2 + 0) * 4 + 1) * 128 + d] = k1;
    scr[((half * 2 + 0) * 4 + 2) * 128 + d] = k2;
    scr[((half * 2 + 0) * 4 + 3) * 128 + d] = k3;
    scr[((half * 2 + 1) * 4 + 0) * 128 + d] = v0;
    scr[((half * 2 + 1) * 4 + 1) * 128 + d] = v1;
    scr[((half * 2 + 1) * 4 + 2) * 128 + d] = v2;
    scr[((half * 2 + 1) * 4 + 3) * 128 + d] = v3;
    __syncthreads();
    if (half == 0) {
        float bkd = bk[d];
        #pragma unroll
        for (int j = 0; j < 4; j++) {
            int m = m0 + j;
            float kvj = bkd + scr[(0 * 4 + j) * 128 + d] + scr[(2 * 4 + j) * 128 + d];
            int kk = d >> 5, lq = (d >> 3) & 3, jj = d & 7;
            int fid = (m >> 4) * 4 + kk;
            k_t[(b << 14) + fid * 512 + (lq * 16 + (m & 15)) * 8 + jj] = f2b(kvj);
        }
    } else {
        float bvtd = bvt[d];
        #pragma unroll
        for (int j = 0; j < 4; j++) {
            int m = m0 + j;
            float vvj = bvtd + scr[(1 * 4 + j) * 128 + d] + scr[(3 * 4 + j) * 128 + d];
            int df = d >> 4, kk2 = m >> 5, lq2 = (m >> 3) & 3, j2 = m & 7;
            int fid2 = df * 4 + kk2;
            vT_t[(b << 14) + fid2 * 512 + (lq2 * 16 + (d & 15)) * 8 + j2] = f2b(vvj);
        }
    }
}

// ---------------- Kernel 4: fused MFMA attention, 64 tokens/block (R16-proven) ----------------
__global__ __launch_bounds__(256, 3) void attn_kernel(
    const float* __restrict__ hidden,
    const short* __restrict__ WqTt, const float* __restrict__ bq,
    const short* __restrict__ k_t, const short* __restrict__ vT_t,
    const short* __restrict__ WoTt, const float* __restrict__ bo,
    const int* __restrict__ nvis,
    float* __restrict__ out) {
    // XCD swizzle: XCD x owns batch x (K/V L2-resident)
    int wg = (blockIdx.x & 7) * 128 + (blockIdx.x >> 3);
    int b  = wg >> 7;
    int s0 = (wg & 127) * 64;
    int tid = threadIdx.x;
    int lane = tid & 63;
    int w  = tid >> 6;             // wave 0..3
    int lr = lane & 15;
    int lq = lane >> 4;            // quarter 0..3

    // LDS 48KB: ph1: Ab bf16 chunk [0,8K), qP [32K,48K).
    // ph2-3: lg 64x512B swz [0,32K). ph3-4: pP [0,16K), od [16K,32K).
    // ph5: C-stage (16 x 1040B) at [0,16.3K).
    __shared__ __align__(16) char SH[49152];
    char* Ab  = SH;
    char* pPc = SH;
    char* odc = SH + 16384;
    char* qPc = SH + 32768;

    const size_t hrow = (size_t)b * SEQ + s0;
    f32x4 zero = {0.f, 0.f, 0.f, 0.f};

    // ================= phase 1: q = (H @ Wq + bq) * scale =================
    f32x4 acc[4][2];
    #pragma unroll
    for (int rf = 0; rf < 4; rf++) { acc[rf][0] = zero; acc[rf][1] = zero; }

    // Coalesced staging map: instr g (0..3), thread t: row = g*16 + (t>>4),
    // 4 fp32 at float-index (t&15)*4. Per wave-instruction: 4 rows x 256B.
    int rsub = tid >> 4;           // 0..15
    int cfl  = (tid & 15) * 4;
    const float* hA0 = hidden + (hrow + 0 * 16 + rsub) * EMB + cfl;
    const float* hA1 = hidden + (hrow + 1 * 16 + rsub) * EMB + cfl;
    const float* hA2 = hidden + (hrow + 2 * 16 + rsub) * EMB + cfl;
    const float* hA3 = hidden + (hrow + 3 * 16 + rsub) * EMB + cfl;
    int swzA = (rsub & 7) << 4;
    int dA0 = (0 * 16 + rsub) * 128 + (((tid & 15) * 8) ^ swzA);
    int dA1 = (1 * 16 + rsub) * 128 + (((tid & 15) * 8) ^ swzA);
    int dA2 = (2 * 16 + rsub) * 128 + (((tid & 15) * 8) ^ swzA);
    int dA3 = (3 * 16 + rsub) * 128 + (((tid & 15) * 8) ^ swzA);

    float4 pa0[4], pa1[4], pa2[4];
    short8v Wa[4], Wb[4];

#define LOADA(C, PA) do { \
    PA[0] = *(const float4*)(hA0 + (C) * 64); \
    PA[1] = *(const float4*)(hA1 + (C) * 64); \
    PA[2] = *(const float4*)(hA2 + (C) * 64); \
    PA[3] = *(const float4*)(hA3 + (C) * 64); } while (0)

#define LOADW(C, W) do { \
    const short* wp = WqTt + ((C) * 16 + 2 * w) * 512 + lane * 8; \
    W[0] = *(const short8v*)(wp); \
    W[1] = *(const short8v*)(wp + 512); \
    W[2] = *(const short8v*)(wp + 8 * 512); \
    W[3] = *(const short8v*)(wp + 9 * 512); } while (0)

#define STORE_A(PA) do { \
    unsigned long long v0_ = (unsigned long long)cvtpk(PA[0].z, PA[0].w) << 32 | cvtpk(PA[0].x, PA[0].y); \
    unsigned long long v1_ = (unsigned long long)cvtpk(PA[1].z, PA[1].w) << 32 | cvtpk(PA[1].x, PA[1].y); \
    unsigned long long v2_ = (unsigned long long)cvtpk(PA[2].z, PA[2].w) << 32 | cvtpk(PA[2].x, PA[2].y); \
    unsigned long long v3_ = (unsigned long long)cvtpk(PA[3].z, PA[3].w) << 32 | cvtpk(PA[3].x, PA[3].y); \
    *(unsigned long long*)(Ab + dA0) = v0_; \
    *(unsigned long long*)(Ab + dA1) = v1_; \
    *(unsigned long long*)(Ab + dA2) = v2_; \
    *(unsigned long long*)(Ab + dA3) = v3_; } while (0)

#define COMPUTE(W) do { \
    _Pragma("unroll") \
    for (int ks = 0; ks < 2; ks++) { \
        _Pragma("unroll") \
        for (int rf = 0; rf < 4; rf++) { \
            int row = rf * 16 + lr; \
            short8v fa = *(short8v*)(Ab + ((row * 128 + ks * 64 + lq * 16) ^ ((row & 7) << 4))); \
            acc[rf][0] = MFMA(fa, W[ks * 2 + 0], acc[rf][0]); \
            acc[rf][1] = MFMA(fa, W[ks * 2 + 1], acc[rf][1]); \
        } } } while (0)

// R12/R16 schedule: vmcnt never force-drains; LOADW(c+2) after COMPUTE.
#define ITER(c, PA, WW, DO_A, DO_W) do { \
    __builtin_amdgcn_s_barrier();                 /* readers of chunk c-1 done */ \
    STORE_A(PA);                                  /* counted wait: A(c)       */ \
    if (DO_A) LOADA((c) + 3, PA); \
    asm volatile("s_waitcnt lgkmcnt(0)" ::: "memory"); \
    __builtin_amdgcn_sched_barrier(0); \
    __builtin_amdgcn_s_barrier();                 /* chunk c visible          */ \
    COMPUTE(WW);                                  /* counted wait: W(c)       */ \
    if (DO_W) LOADW((c) + 2, WW);                 /* refill consumed slot     */ \
    } while (0)

    // prologue — queue: W0, W1, A0, A1, A2
    LOADW(0, Wa);
    LOADW(1, Wb);
    LOADA(0, pa0);
    LOADA(1, pa1);
    LOADA(2, pa2);

    ITER(0,  pa0, Wa, 1, 1);
    ITER(1,  pa1, Wb, 1, 1);
    ITER(2,  pa2, Wa, 1, 1);
    ITER(3,  pa0, Wb, 1, 1);
    ITER(4,  pa1, Wa, 1, 1);
    ITER(5,  pa2, Wb, 1, 1);
    ITER(6,  pa0, Wa, 1, 1);
    ITER(7,  pa1, Wb, 1, 1);
    ITER(8,  pa2, Wa, 1, 1);
    ITER(9,  pa0, Wb, 1, 1);
    ITER(10, pa1, Wa, 1, 1);
    ITER(11, pa2, Wb, 1, 1);
    ITER(12, pa0, Wa, 1, 1);
    ITER(13, pa1, Wb, 0, 1);
    ITER(14, pa2, Wa, 0, 0);
    ITER(15, pa0, Wb, 0, 0);

    {
        const float scale = 0.08838834764831845f;  // 128^-0.5
        int d0 = w * 32 + lr;
        float bq0 = bq[d0], bq1 = bq[d0 + 16];
        #pragma unroll
        for (int rf = 0; rf < 4; rf++)
            #pragma unroll
            for (int r = 0; r < 4; r++) {
                int row = rf * 16 + lq * 4 + r;
                int x = (row & 7) << 4;
                *(short*)(qPc + row * 256 + ((d0 * 2) ^ x))        = f2b((acc[rf][0][r] + bq0) * scale);
                *(short*)(qPc + row * 256 + (((d0 + 16) * 2) ^ x)) = f2b((acc[rf][1][r] + bq1) * scale);
            }
    }
    __syncthreads();   // B1: q visible; Ab dead -> lg region live

    // ================= phase 2: logits = q @ K^T =================
    {
        f32x4 l[4][2];
        #pragma unroll
        for (int rf = 0; rf < 4; rf++) { l[rf][0] = zero; l[rf][1] = zero; }
        const short* kbase = k_t + (b << 14) + (2 * w) * 4 * 512 + lane * 8;
        #pragma unroll
        for (int kk = 0; kk < 4; kk++) {
            const short8v fb0 = *(const short8v*)(kbase + kk * 512);
            const short8v fb1 = *(const short8v*)(kbase + (4 + kk) * 512);
            #pragma unroll
            for (int rf = 0; rf < 4; rf++) {
                int row = rf * 16 + lr;
                int x = (row & 7) << 4;
                short8v fa = *(short8v*)(qPc + row * 256 + ((kk * 64 + lq * 16) ^ x));
                l[rf][0] = MFMA(fa, fb0, l[rf][0]);
                l[rf][1] = MFMA(fa, fb1, l[rf][1]);
            }
        }
        #pragma unroll
        for (int rf = 0; rf < 4; rf++)
            #pragma unroll
            for (int r = 0; r < 4; r++) {
                int row = rf * 16 + lq * 4 + r;
                int x = (row & 7) << 4;
                *(float*)(SH + row * 512 + (((w * 32 + lr) * 4) ^ x))      = l[rf][0][r];
                *(float*)(SH + row * 512 + (((w * 32 + 16 + lr) * 4) ^ x)) = l[rf][1][r];
            }
    }
    __syncthreads();   // B2: logits visible

    // ================= phase 3: masked softmax (4 threads/token, 32 m each) =================
    {
        int t = tid >> 2, sub = tid & 3;
        int nv = nvis[b * SEQ + s0 + t];
        int x = (t & 7) << 4;
        float pv[32];
        #pragma unroll
        for (int u = 0; u < 8; u++) {
            float4 v = *(const float4*)(SH + t * 512 + ((sub * 128 + u * 16) ^ x));
            pv[u * 4]     = v.x; pv[u * 4 + 1] = v.y;
            pv[u * 4 + 2] = v.z; pv[u * 4 + 3] = v.w;
        }
        int base_m = sub * 32;
        float mx = -3.0e38f;
        #pragma unroll
        for (int i = 0; i < 32; i++)
            mx = (base_m + i < nv) ? fmaxf(mx, pv[i]) : mx;
        mx = fmaxf(mx, __shfl_xor(mx, 1));
        mx = fmaxf(mx, __shfl_xor(mx, 2));
        float sum = 0.f;
        #pragma unroll
        for (int i = 0; i < 32; i++) {
            float e = (base_m + i < nv) ? __expf(pv[i] - mx) : 0.f;
            pv[i] = e;
            sum += e;
        }
        sum += __shfl_xor(sum, 1);
        sum += __shfl_xor(sum, 2);
        float inv = (nv > 0) ? 1.0f / sum : 0.f;

        __syncthreads();   // B3: all lg reads done; region becomes pP/od

        #pragma unroll
        for (int u = 0; u < 4; u++) {
            union { short8v s; unsigned uu[4]; } p;
            #pragma unroll
            for (int i = 0; i < 4; i++)
                p.uu[i] = cvtpk(pv[u * 8 + 2 * i] * inv, pv[u * 8 + 2 * i + 1] * inv);
            *(short8v*)(pPc + t * 256 + ((sub * 64 + u * 16) ^ x)) = p.s;
        }
    }
    __syncthreads();   // B4: P visible

    // ================= phase 4: od = P @ V =================
    {
        f32x4 o[4][2];
        #pragma unroll
        for (int rf = 0; rf < 4; rf++) { o[rf][0] = zero; o[rf][1] = zero; }
        const short* vbase = vT_t + (b << 14) + (2 * w) * 4 * 512 + lane * 8;
        #pragma unroll
        for (int kk = 0; kk < 4; kk++) {
            const short8v fb0 = *(const short8v*)(vbase + kk * 512);
            const short8v fb1 = *(const short8v*)(vbase + (4 + kk) * 512);
            #pragma unroll
            for (int rf = 0; rf < 4; rf++) {
                int row = rf * 16 + lr;
                int x = (row & 7) << 4;
                short8v fa = *(short8v*)(pPc + row * 256 + ((kk * 64 + lq * 16) ^ x));
                o[rf][0] = MFMA(fa, fb0, o[rf][0]);
                o[rf][1] = MFMA(fa, fb1, o[rf][1]);
            }
        }
        int d0 = w * 32 + lr;
        #pragma unroll
        for (int rf = 0; rf < 4; rf++)
            #pragma unroll
            for (int r = 0; r < 4; r++) {
                int row = rf * 16 + lq * 4 + r;
                int x = (row & 7) << 4;
                *(short*)(odc + row * 256 + ((d0 * 2) ^ x))        = f2b(o[rf][0][r]);
                *(short*)(odc + row * 256 + (((d0 + 16) * 2) ^ x)) = f2b(o[rf][1][r]);
            }
    }
    __syncthreads();   // B5: od visible

    // ===== phase 5: out = od @ Wo + bo — full-line writes via LDS C-stage =====
    {
        short8v af[4][4];
        #pragma unroll
        for (int rf = 0; rf < 4; rf++)
            #pragma unroll
            for (int kk = 0; kk < 4; kk++) {
                int row = rf * 16 + lr;
                int x = (row & 7) << 4;
                af[rf][kk] = *(short8v*)(odc + row * 256 + ((kk * 64 + lq * 16) ^ x));
            }
        __syncthreads();   // B6: od fully consumed -> SH[0,32K) free for C-stage

        float* cst = (float*)SH;        // 16 rows x 260 dwords (1040B stride)
        int srow2 = tid >> 4;           // coop-store row 0..15
        int scidx = (tid & 15) * 4;     // coop-store col base (floats)

        #pragma unroll
        for (int grp = 0; grp < 4; grp++) {
            f32x4 ac[4][4];
            #pragma unroll
            for (int rf = 0; rf < 4; rf++)
                #pragma unroll
                for (int cf = 0; cf < 4; cf++) ac[rf][cf] = zero;
            #pragma unroll
            for (int kk = 0; kk < 4; kk++) {
                #pragma unroll
                for (int cf = 0; cf < 4; cf++) {
                    const short8v bb = *(const short8v*)(WoTt
                        + ((grp * 16 + w * 4 + cf) * 4 + kk) * 512 + lane * 8);
                    #pragma unroll
                    for (int rf = 0; rf < 4; rf++)
                        ac[rf][cf] = MFMA(af[rf][kk], bb, ac[rf][cf]);
                }
            }
            #pragma unroll
            for (int rf = 0; rf < 4; rf++) {
                #pragma unroll
                for (int cf = 0; cf < 4; cf++)
                    #pragma unroll
                    for (int r = 0; r < 4; r++)
                        cst[(lq * 4 + r) * 260 + w * 64 + cf * 16 + lr] = ac[rf][cf][r];
                __syncthreads();
                #pragma unroll
                for (int i = 0; i < 4; i++) {
                    int cidx = scidx + i * 64;
                    float4 v = *(const float4*)(cst + srow2 * 260 + cidx);
                    float4 b4 = *(const float4*)(bo + grp * 256 + cidx);
                    v.x += b4.x; v.y += b4.y; v.z += b4.z; v.w += b4.w;
                    *(float4*)(&out[(hrow + rf * 16 + srow2) * EMB + grp * 256 + cidx]) = v;
                }
                __syncthreads();
            }
        }
    }
}

extern "C" void kernel_launch(void* const* d_in, const int* in_sizes, int n_in,
                              void* d_out, int out_size, void* d_ws, size_t ws_size,
                              hipStream_t stream) {
    const int*   ids    = (const int*)d_in[0];
    const float* hidden = (const float*)d_in[1];
    const float* Wv     = (const float*)d_in[2];
    const float* bv     = (const float*)d_in[3];
    const float* Wq     = (const float*)d_in[4];
    const float* bq     = (const float*)d_in[5];
    const float* Wk     = (const float*)d_in[6];
    const float* bk     = (const float*)d_in[7];
    const float* Wvt    = (const float*)d_in[8];
    const float* bvt    = (const float*)d_in[9];
    const float* Wo     = (const float*)d_in[10];
    const float* bo     = (const float*)d_in[11];

    char* ws = (char*)d_ws;
    int*   pos   = (int*)ws;                                   // 4 KB
    int*   nvis  = (int*)(ws + (4 << 10));                     // 256 KB
    short* k_t   = (short*)(ws + (260 << 10));                 // 256 KB tiled
    short* vT_t  = (short*)(ws + (516 << 10));                 // 256 KB tiled
    short* WqTt  = (short*)(ws + (772 << 10));                 // 256 KB tiled
    short* WoTt  = (short*)(ws + (1028 << 10));                // 256 KB tiled

    seg_kernel<<<NB, 1024, 0, stream>>>(ids, pos, nvis);
    prep_w<<<64, 256, 0, stream>>>(Wq, Wo, WqTt, WoTt);
    dim3 g2(32, NB);
    statkv_kernel<<<g2, 256, 0, stream>>>(hidden, Wv, bv, Wk, bk, Wvt, bvt, pos, k_t, vT_t);
    attn_kernel<<<NB * (SEQ / 64), 256, 0, stream>>>(hidden, WqTt, bq, k_t, vT_t, WoTt, bo,
                                                     nvis, (float*)d_out);
}